// Round 3
// baseline (720.036 us; speedup 1.0000x reference)
//
#include <hip/hip_runtime.h>

typedef __attribute__((ext_vector_type(8))) short short8;
typedef __attribute__((ext_vector_type(4))) float f32x4;
typedef __attribute__((ext_vector_type(4))) int i32x4;

#define NPIX 65536
#define RED_M1 0
#define RED_MX 512
#define RED_AGG 1024
#define RED_S1 33792

__device__ __forceinline__ float b2f(unsigned short u) {
  union { unsigned int i; float f; } z; z.i = ((unsigned int)u) << 16; return z.f;
}
__device__ __forceinline__ unsigned short f2b(float f) {
  union { float f; unsigned int i; } z; z.f = f;
  unsigned int r = z.i + 0x7fffu + ((z.i >> 16) & 1u);
  return (unsigned short)(r >> 16);
}
__device__ __forceinline__ unsigned int packbf(float a, float b) {
  return (unsigned int)f2b(a) | ((unsigned int)f2b(b) << 16);
}
// packed f32->bf16 (RNE), 1 instr per 2 values
__device__ __forceinline__ int cvtpk(float a, float b) {
  int r;
  asm("v_cvt_pk_bf16_f32 %0, %1, %2" : "=v"(r) : "v"(a), "v"(b));
  return r;
}

// Build MFMA A-fragment weights (bf16) for both convs:
// wA[conv][tap][kb][mt][lane][j] = W[o=mt*16+(lane&15)][c=kb*32+(lane>>4)*8+j][tap]
// Also zero the reduction region (ws is 0xAA-poisoned before every call).
__global__ __launch_bounds__(256) void prep_kernel(
    const float* __restrict__ W1, const float* __restrict__ W2,
    unsigned short* __restrict__ wA, float* __restrict__ red)
{
  const int i = blockIdx.x * 256 + threadIdx.x;
  if (i < 73728) {
    const float* W = (i < 36864) ? W1 : W2;
    const int e = (i < 36864) ? i : (i - 36864);
    const int j    = e & 7;
    const int lane = (e >> 3) & 63;
    const int mt   = (e >> 9) & 3;
    const int kb   = (e >> 11) & 1;
    const int tap  = e >> 12;                 // 0..8 = dy*3+dx
    const int o = mt * 16 + (lane & 15);
    const int c = kb * 32 + ((lane >> 4) << 3) + j;
    wA[i] = f2b(W[o * 576 + c * 9 + tap]);
  } else if (i < 73728 + 33800) {
    red[i - 73728] = 0.0f;
  }
}

// Pass 1 (Gram restructure): Q/K projections via 16x16x32 bf16 MFMA.
// Q: L2-normalized, wave-private LDS transpose (half-wave rounds), NHWC store.
// K: only 1/||K|| survives (dk, 1KB LDS). agg_kv is NOT formed here; instead
// the weighted Gram M = X diag(dk) X^T is accumulated via MFMA with
// k = pixels, reading x in NATURAL NCHW layout (coalesced float4, no
// transpose). m1 = X dk, mx = X 1, s1 = sum(dk) accumulate alongside.
// prep2 reassembles agg/ksum/vsum from (M, m1, mx, s1) algebraically.
#define PROJ(WM, BM)                                                           \
    {                                                                          \
      _Pragma("unroll")                                                        \
      for (int mt = 0; mt < 4; ++mt) {                                         \
        const f32x4 bb = *(const f32x4*)((BM) + mt * 16 + g * 4);              \
        _Pragma("unroll")                                                      \
        for (int nt = 0; nt < 4; ++nt) acc[mt][nt] = bb;                       \
      }                                                                        \
      _Pragma("unroll")                                                        \
      for (int kb = 0; kb < 2; ++kb) {                                         \
        short8 af[4];                                                          \
        _Pragma("unroll")                                                      \
        for (int mt = 0; mt < 4; ++mt) {                                       \
          const float* wp = (WM) + mt * 1024 + wrow + kb * 32;                 \
          const f32x4 w0 = *(const f32x4*)wp;                                  \
          const f32x4 w1 = *(const f32x4*)(wp + 4);                            \
          union { i32x4 i; short8 s; } uw;                                     \
          uw.i.x = cvtpk(w0.x, w0.y); uw.i.y = cvtpk(w0.z, w0.w);              \
          uw.i.z = cvtpk(w1.x, w1.y); uw.i.w = cvtpk(w1.z, w1.w);              \
          af[mt] = uw.s;                                                       \
        }                                                                      \
        _Pragma("unroll")                                                      \
        for (int mt = 0; mt < 4; ++mt)                                         \
          _Pragma("unroll")                                                    \
          for (int nt = 0; nt < 4; ++nt)                                       \
            acc[mt][nt] = __builtin_amdgcn_mfma_f32_16x16x32_bf16(             \
                af[mt], bf[nt][kb], acc[mt][nt], 0, 0, 0);                     \
      }                                                                        \
    }

__global__ __launch_bounds__(256, 3) void qkv_kernel(
    const float* __restrict__ x,
    const float* __restrict__ Wq, const float* __restrict__ bq,
    const float* __restrict__ Wk, const float* __restrict__ bk,
    unsigned short* __restrict__ Qn, float* __restrict__ red)
{
  __shared__ __align__(16) unsigned short qsc[4 * 2304];  // 18.4KB Q transpose
  __shared__ __align__(16) float dkbuf[256];              // per-iter px scales
  const int b = blockIdx.y;
  const int t = threadIdx.x;
  const int w = t >> 6, l = t & 63, g = l >> 4, l15 = l & 15;
  const int wrow = l15 * 64 + g * 8;     // per-lane W row-slice base (floats)
  const size_t xb = (size_t)b * 64 * NPIX;

  const f32x4 zero = {0.f, 0.f, 0.f, 0.f};
  f32x4 Mw[4] = {zero, zero, zero, zero};
  float m1p = 0.f, mxp = 0.f, s1p = 0.f;

  for (int it = 0; it < 4; ++it) {
    const int pxblk = (blockIdx.x << 10) + (it << 8);
    const int pxw = pxblk + (w << 6);    // wave px base

    // ---- x B-fragments (ch-contiguous per lane) for the projections ----
    short8 bf[4][2];
#pragma unroll
    for (int nt = 0; nt < 4; ++nt) {
      const float* xp = x + xb + (size_t)(g * 8) * NPIX + pxw + nt * 16 + l15;
#pragma unroll
      for (int kb = 0; kb < 2; ++kb) {
        float f[8];
#pragma unroll
        for (int j = 0; j < 8; ++j)
          f[j] = xp[(size_t)(kb * 32 + j) * NPIX];
        union { i32x4 i; short8 s; } u;
        u.i.x = cvtpk(f[0], f[1]); u.i.y = cvtpk(f[2], f[3]);
        u.i.z = cvtpk(f[4], f[5]); u.i.w = cvtpk(f[6], f[7]);
        bf[nt][kb] = u.s;
      }
    }

    f32x4 acc[4][4];

    // ---- Q: project, normalize, wave-private LDS transpose, NHWC store ----
    PROJ(Wq, bq);
    {
      float rq[4];
#pragma unroll
      for (int nt = 0; nt < 4; ++nt) {
        float ss = 0.f;
#pragma unroll
        for (int mt = 0; mt < 4; ++mt)
#pragma unroll
          for (int r = 0; r < 4; ++r)
            ss = fmaf(acc[mt][nt][r], acc[mt][nt][r], ss);
        ss += __shfl_xor(ss, 16);
        ss += __shfl_xor(ss, 32);
        rq[nt] = rsqrtf(ss);
      }
      unsigned int* sw = (unsigned int*)qsc + w * 1152;  // 32px * 36 uints
#pragma unroll
      for (int h = 0; h < 2; ++h) {
#pragma unroll
        for (int mt = 0; mt < 4; ++mt)
#pragma unroll
          for (int n2 = 0; n2 < 2; ++n2) {
            const int nt = h * 2 + n2;
            unsigned int* dst = sw + (n2 * 16 + l15) * 36 + mt * 8 + g * 2;
            dst[0] = (unsigned)cvtpk(acc[mt][nt][0] * rq[nt],
                                     acc[mt][nt][1] * rq[nt]);
            dst[1] = (unsigned)cvtpk(acc[mt][nt][2] * rq[nt],
                                     acc[mt][nt][3] * rq[nt]);
          }
        const uint4* rr4 = (const uint4*)qsc + w * 288;  // 32px * 9 uint4
#pragma unroll
        for (int k4 = 0; k4 < 4; ++k4) {
          const int p = (k4 << 3) + (l >> 3);
          const int ch8 = l & 7;
          *(uint4*)(Qn + ((size_t)b * NPIX + pxw + h * 32 + p) * 64 + ch8 * 8) =
              rr4[p * 9 + ch8];
        }
      }
    }

    // ---- K: project, keep only 1/||K|| per px -> dk LDS; s1 partial ----
    PROJ(Wk, bk);
    {
      float rk[4];
#pragma unroll
      for (int nt = 0; nt < 4; ++nt) {
        float ss = 0.f;
#pragma unroll
        for (int mt = 0; mt < 4; ++mt)
#pragma unroll
          for (int r = 0; r < 4; ++r)
            ss = fmaf(acc[mt][nt][r], acc[mt][nt][r], ss);
        ss += __shfl_xor(ss, 16);
        ss += __shfl_xor(ss, 32);
        rk[nt] = rsqrtf(ss);
      }
      s1p += rk[0] + rk[1] + rk[2] + rk[3];
      if (l < 16) {
#pragma unroll
        for (int nt = 0; nt < 4; ++nt)
          dkbuf[(w << 6) + nt * 16 + l15] = rk[nt];
      }
    }
    __syncthreads();

    // ---- Gram: M += X diag(dk) X^T over 256 px, natural-layout loads ----
    // A-frag: ch = 16w+l15 (scaled by dk); B-frags: ch = nt*16+l15.
#pragma unroll
    for (int s = 0; s < 8; ++s) {
      const int pk = pxblk + s * 32 + g * 8;
      const float* xa = x + xb + (size_t)(w * 16 + l15) * NPIX + pk;
      const f32x4 a0 = *(const f32x4*)xa;
      const f32x4 a1 = *(const f32x4*)(xa + 4);
      const f32x4 d0 = *(const f32x4*)(dkbuf + s * 32 + g * 8);
      const f32x4 d1 = *(const f32x4*)(dkbuf + s * 32 + g * 8 + 4);
      const float p0 = a0.x * d0.x, p1 = a0.y * d0.y;
      const float p2 = a0.z * d0.z, p3 = a0.w * d0.w;
      const float p4 = a1.x * d1.x, p5 = a1.y * d1.y;
      const float p6 = a1.z * d1.z, p7 = a1.w * d1.w;
      m1p += p0 + p1 + p2 + p3 + p4 + p5 + p6 + p7;
      mxp += a0.x + a0.y + a0.z + a0.w + a1.x + a1.y + a1.z + a1.w;
      union { i32x4 i; short8 s8; } ua;
      ua.i.x = cvtpk(p0, p1); ua.i.y = cvtpk(p2, p3);
      ua.i.z = cvtpk(p4, p5); ua.i.w = cvtpk(p6, p7);
#pragma unroll
      for (int nt = 0; nt < 4; ++nt) {
        const float* xbp = x + xb + (size_t)(nt * 16 + l15) * NPIX + pk;
        const f32x4 b0 = *(const f32x4*)xbp;
        const f32x4 b1 = *(const f32x4*)(xbp + 4);
        union { i32x4 i; short8 s8; } ub;
        ub.i.x = cvtpk(b0.x, b0.y); ub.i.y = cvtpk(b0.z, b0.w);
        ub.i.z = cvtpk(b1.x, b1.y); ub.i.w = cvtpk(b1.z, b1.w);
        Mw[nt] = __builtin_amdgcn_mfma_f32_16x16x32_bf16(
            ua.s8, ub.s8, Mw[nt], 0, 0, 0);
      }
    }
    __syncthreads();   // dkbuf reused next iter
  }

  // ---- reductions ----
  m1p += __shfl_xor(m1p, 16); m1p += __shfl_xor(m1p, 32);
  mxp += __shfl_xor(mxp, 16); mxp += __shfl_xor(mxp, 32);
  if (l < 16) {
    atomicAdd(red + RED_M1 + b * 64 + w * 16 + l15, m1p);
    atomicAdd(red + RED_MX + b * 64 + w * 16 + l15, mxp);
  }
  s1p += __shfl_xor(s1p, 1); s1p += __shfl_xor(s1p, 2);
  s1p += __shfl_xor(s1p, 4); s1p += __shfl_xor(s1p, 8);
  if (l == 0) atomicAdd(red + RED_S1 + b, s1p);
  float* Mb = red + RED_AGG + b * 4096;
#pragma unroll
  for (int nt = 0; nt < 4; ++nt)
#pragma unroll
    for (int r = 0; r < 4; ++r)
      atomicAdd(Mb + (w * 16 + g * 4 + r) * 64 + nt * 16 + l15, Mw[nt][r]);
}

// Prep2: per batch, assemble from (M, m1, mx, s1):
//   ksum = Wk m1 + s1 bk;       vsum = Wv mx + N bv
//   agg  = Wk M Wv^T + (Wk m1) bv^T + bk (Wv m1)^T + s1 bk bv^T
//   C    = Wr agg^T = (Wr Wv) M Wk^T + t3 t1^T + (Wr t2 + s1 t3) bk^T
// with t1 = Wk m1, t2 = Wv m1, t3 = Wr bv  (M symmetric).
// C split into bf16 hi + residual in MFMA A-frag layout; u = Wr vsum.
__global__ __launch_bounds__(256) void prep2_kernel(
    const float* __restrict__ Wk, const float* __restrict__ bk,
    const float* __restrict__ Wv, const float* __restrict__ bv,
    const float* __restrict__ Wr, const float* __restrict__ red,
    unsigned short* __restrict__ Cb, float* __restrict__ u,
    float* __restrict__ ks2)
{
  __shared__ float T[4096];
  __shared__ float P2[4096];
  __shared__ float sm[320];
  const int b = blockIdx.x;
  const int t = threadIdx.x;
  const float* M  = red + RED_AGG + b * 4096;
  const float* m1 = red + RED_M1 + b * 64;
  const float* mx = red + RED_MX + b * 64;
  const float s1 = red[RED_S1 + b];
  if (t < 64) {
    float a = 0.f, c = 0.f, d = 0.f;
    for (int v = 0; v < 64; ++v) {
      a = fmaf(Wk[t * 64 + v], m1[v], a);
      c = fmaf(Wv[t * 64 + v], m1[v], c);
      d = fmaf(Wv[t * 64 + v], mx[v], d);
    }
    sm[t] = a;           // t1 = Wk m1
    sm[64 + t] = c;      // t2 = Wv m1
    sm[128 + t] = d;     // mv = Wv mx
  }
  __syncthreads();
  {
    const int o = t & 63, n0 = (t >> 6) * 16;
    for (int n = n0; n < n0 + 16; ++n) {
      float s = 0.f;
      for (int v = 0; v < 64; ++v) s = fmaf(Wv[o * 64 + v], M[v * 64 + n], s);
      T[o * 64 + n] = s;                    // T = Wv M
    }
  }
  __syncthreads();
  {
    const int o = t & 63, n0 = (t >> 6) * 16;
    for (int n = n0; n < n0 + 16; ++n) {
      float s = 0.f;
      for (int v = 0; v < 64; ++v) s = fmaf(Wr[o * 64 + v], T[v * 64 + n], s);
      P2[o * 64 + n] = s;                   // P2 = Wr Wv M
    }
  }
  if (t < 64) {
    float t3 = 0.f, uu = 0.f, e2 = 0.f;
    for (int v = 0; v < 64; ++v) {
      t3 = fmaf(Wr[t * 64 + v], bv[v], t3);
      uu = fmaf(Wr[t * 64 + v], sm[128 + v], uu);
      e2 = fmaf(Wr[t * 64 + v], sm[64 + v], e2);
    }
    u[b * 64 + t] = uu + 65536.0f * t3;     // Wr(Wv mx + N bv)
    ks2[b * 64 + t] = sm[t] + s1 * bk[t] + 1e-6f;
    sm[192 + t] = t3;                       // Wr bv
    sm[256 + t] = e2 + s1 * t3;             // Wr t2 + s1 t3
  }
  __syncthreads();
  {
    const int o = t & 63, k0 = (t >> 6) * 16;
    for (int k = k0; k < k0 + 16; ++k) {
      float s = fmaf(sm[192 + o], sm[k], sm[256 + o] * bk[k]);
      for (int v = 0; v < 64; ++v) s = fmaf(P2[o * 64 + v], Wk[k * 64 + v], s);
      const int mt = o >> 4, kb = k >> 5;
      const int lane = (o & 15) | (((k >> 3) & 3) << 4);
      const int j = k & 7;
      const unsigned short c1 = f2b(s);
      const float r1 = s - b2f(c1);
      Cb[b * 4096 + ((kb * 4 + mt) * 64 + lane) * 8 + j] = c1;
      Cb[32768 + b * 4096 + ((kb * 4 + mt) * 64 + lane) * 8 + j] = f2b(r1);
    }
  }
}

// Pass 2 (MFMA): attn[o,n] = denom[n]*(u[o] + C[o,:].qn[:,n]) + br[o].
// C = C1 + C2 (bf16 split) -> fp32-accurate. denom from per-lane partial
// dot with ks2 + shfl_xor reduce. Output NHWC bf16 via wave-private LDS
// transpose (no barriers needed).
__global__ __launch_bounds__(256, 2) void attn_kernel(
    const unsigned short* __restrict__ Qn,   // NHWC bf16
    const unsigned short* __restrict__ Cb,   // C1||C2 A-frags
    const float* __restrict__ u,
    const float* __restrict__ ks2,
    const float* __restrict__ br,
    unsigned short* __restrict__ attn)       // NHWC bf16
{
  __shared__ __align__(16) unsigned short att[256 * 72];
  const int b = blockIdx.y;
  const int t = threadIdx.x;
  const int w = t >> 6, l = t & 63, g = l >> 4, l15 = l & 15;

  short8 af[2][2][4];  // [lvl][kb][mt]
#pragma unroll
  for (int lvl = 0; lvl < 2; ++lvl)
#pragma unroll
    for (int kb = 0; kb < 2; ++kb)
#pragma unroll
      for (int mt = 0; mt < 4; ++mt)
        af[lvl][kb][mt] = *(const short8*)(
            Cb + lvl * 32768 + b * 4096 + ((kb * 4 + mt) * 64 + l) * 8);
  f32x4 uu[4], brf[4];
#pragma unroll
  for (int mt = 0; mt < 4; ++mt) {
    uu[mt]  = *(const f32x4*)(u + b * 64 + mt * 16 + g * 4);
    brf[mt] = *(const f32x4*)(br + mt * 16 + g * 4);
  }
  float ksl[16];
#pragma unroll
  for (int kb = 0; kb < 2; ++kb)
#pragma unroll
    for (int j = 0; j < 8; ++j)
      ksl[kb * 8 + j] = ks2[b * 64 + kb * 32 + g * 8 + j];

  for (int it = 0; it < 4; ++it) {
    const int pxw = (blockIdx.x << 10) + (it << 8) + (w << 6);
    short8 qf[4][2];
    float denom[4];
#pragma unroll
    for (int nt = 0; nt < 4; ++nt) {
      const unsigned short* qp =
          Qn + ((size_t)b * NPIX + pxw + nt * 16 + l15) * 64 + g * 8;
      qf[nt][0] = *(const short8*)qp;
      qf[nt][1] = *(const short8*)(qp + 32);
      float ss = 0.f;
#pragma unroll
      for (int kb = 0; kb < 2; ++kb)
#pragma unroll
        for (int j = 0; j < 8; ++j)
          ss = fmaf(b2f((unsigned short)qf[nt][kb][j]), ksl[kb * 8 + j], ss);
      ss += __shfl_xor(ss, 16);
      ss += __shfl_xor(ss, 32);
      denom[nt] = 1.0f / (65536.0f + ss);
    }
    f32x4 acc[4][4];
#pragma unroll
    for (int mt = 0; mt < 4; ++mt)
#pragma unroll
      for (int nt = 0; nt < 4; ++nt) acc[mt][nt] = uu[mt];
#pragma unroll
    for (int kb = 0; kb < 2; ++kb)
#pragma unroll
      for (int mt = 0; mt < 4; ++mt)
#pragma unroll
        for (int nt = 0; nt < 4; ++nt) {
          acc[mt][nt] = __builtin_amdgcn_mfma_f32_16x16x32_bf16(
              af[0][kb][mt], qf[nt][kb], acc[mt][nt], 0, 0, 0);
          acc[mt][nt] = __builtin_amdgcn_mfma_f32_16x16x32_bf16(
              af[1][kb][mt], qf[nt][kb], acc[mt][nt], 0, 0, 0);
        }
    // epilogue: val = acc*denom + br; wave-private LDS transpose, dense store
    unsigned int* sw = (unsigned int*)att + w * 2304;
#pragma unroll
    for (int mt = 0; mt < 4; ++mt)
#pragma unroll
      for (int nt = 0; nt < 4; ++nt) {
        const int px = nt * 16 + l15;
        unsigned int* dst = sw + px * 36 + mt * 8 + g * 2;
        dst[0] = (unsigned)cvtpk(fmaf(acc[mt][nt][0], denom[nt], brf[mt][0]),
                                 fmaf(acc[mt][nt][1], denom[nt], brf[mt][1]));
        dst[1] = (unsigned)cvtpk(fmaf(acc[mt][nt][2], denom[nt], brf[mt][2]),
                                 fmaf(acc[mt][nt][3], denom[nt], brf[mt][3]));
      }
    const uint4* rr4 = (const uint4*)att + w * 576;
#pragma unroll
    for (int k8 = 0; k8 < 8; ++k8) {
      const int p = (k8 << 3) + (l >> 3);
      const int ch8 = l & 7;
      *(uint4*)(attn + ((size_t)b * NPIX + pxw + p) * 64 + ch8 * 8) =
          rr4[p * 9 + ch8];
    }
  }
}

// 3x3 SAME conv, 64->64 ch, bf16 MFMA implicit GEMM.
template <int EPI>
__global__ __launch_bounds__(256, 3) void conv3_kernel(
    const unsigned short* __restrict__ in,   // NHWC bf16
    const unsigned short* __restrict__ wA,   // A-frag weights bf16
    const float* __restrict__ bias,
    const float* __restrict__ xin,           // NCHW fp32 (EPI=1)
    unsigned short* __restrict__ outh,       // NHWC bf16 (EPI=0)
    float* __restrict__ outf)                // NCHW fp32 (EPI=1)
{
  __shared__ __align__(16) unsigned short tile[10 * 34 * 72];
  const int bz = blockIdx.z;
  const int ty0 = blockIdx.y << 3;
  const int tx0 = blockIdx.x << 5;
  const int tid = threadIdx.x;
  const size_t nb = (size_t)bz * NPIX;

  // ---- stage NHWC tile (halo=1, zero-pad SAME) ----
  for (int s = tid; s < 2720; s += 256) {
    const int g = s & 7;
    const int pix = s >> 3;          // 0..339
    const int xx = pix % 34;
    const int row = pix / 34;
    const int gx = tx0 + xx - 1;
    const int gy = ty0 + row - 1;
    uint4 v = {0u, 0u, 0u, 0u};
    if ((unsigned)gx < 256u && (unsigned)gy < 256u)
      v = *(const uint4*)(in + ((nb + (gy << 8) + gx) << 6) + (g << 3));
    *(uint4*)(tile + pix * 72 + (g << 3)) = v;
  }
  __syncthreads();

  const int w = tid >> 6, lane = tid & 63, q = lane >> 4, l = lane & 15;
  f32x4 acc[4][4];
  {
#pragma unroll
    for (int mt = 0; mt < 4; ++mt) {
      const f32x4 bb = *(const f32x4*)(bias + mt * 16 + q * 4);
#pragma unroll
      for (int nt = 0; nt < 4; ++nt) acc[mt][nt] = bb;
    }
  }
  const short8* tp = (const short8*)tile;   // 72 shorts = 9 short8 per pixel
  for (int tap = 0; tap < 9; ++tap) {
    const int dy = tap / 3, dx = tap - dy * 3;
#pragma unroll
    for (int kb = 0; kb < 2; ++kb) {
      const unsigned short* wp = wA + (tap * 2 + kb) * 2048 + lane * 8;
      short8 af[4];
#pragma unroll
      for (int mt = 0; mt < 4; ++mt) af[mt] = *(const short8*)(wp + mt * 512);
      short8 bf[4];
#pragma unroll
      for (int nt = 0; nt < 4; ++nt) {
        const int yl = (w << 1) + (nt >> 1) + dy;           // 0..9
        const int xl = ((nt & 1) << 4) + l + dx;            // 0..33
        bf[nt] = tp[(yl * 34 + xl) * 9 + (kb << 2) + q];
      }
#pragma unroll
      for (int mt = 0; mt < 4; ++mt)
#pragma unroll
        for (int nt = 0; nt < 4; ++nt)
          acc[mt][nt] = __builtin_amdgcn_mfma_f32_16x16x32_bf16(
              af[mt], bf[nt], acc[mt][nt], 0, 0, 0);
    }
  }

  if (EPI == 0) {
    // NHWC bf16 epilogue: transpose C-frag -> [pixel][o] in LDS, dense store
    __syncthreads();                          // all waves done reading tile
    unsigned int* wreg = (unsigned int*)tile + w * 2304;   // 64 px * 36 uints
#pragma unroll
    for (int mt = 0; mt < 4; ++mt)
#pragma unroll
      for (int nt = 0; nt < 4; ++nt) {
        const int p = ((nt >> 1) << 5) + ((nt & 1) << 4) + l;
        unsigned int* dst = wreg + p * 36 + (mt << 3) + (q << 1);
        dst[0] = packbf(acc[mt][nt][0], acc[mt][nt][1]);
        dst[1] = packbf(acc[mt][nt][2], acc[mt][nt][3]);
      }
    __syncthreads();
    const uint4* rreg = (const uint4*)tile + w * 576;      // 64 px * 9 uint4
#pragma unroll
    for (int k = 0; k < 8; ++k) {
      const int p = (k << 3) + (lane >> 3);
      const int ch = lane & 7;
      const int gx = tx0 + (p & 31);
      const int gy = ty0 + (w << 1) + (p >> 5);
      *(uint4*)(outh + ((nb + (gy << 8) + gx) << 6) + (ch << 3)) =
          rreg[p * 9 + ch];
    }
  } else {
    // fused epilogue: out = conv*x + x, NCHW fp32
#pragma unroll
    for (int mt = 0; mt < 4; ++mt)
#pragma unroll
      for (int nt = 0; nt < 4; ++nt) {
        const int gx = tx0 + ((nt & 1) << 4) + l;
        const int gy = ty0 + (w << 1) + (nt >> 1);
#pragma unroll
        for (int r = 0; r < 4; ++r) {
          const int o = (mt << 4) + (q << 2) + r;
          const size_t idx = (((size_t)bz * 64 + o) << 16) + (gy << 8) + gx;
          const float xo = xin[idx];
          outf[idx] = fmaf(acc[mt][nt][r], xo, xo);
        }
      }
  }
}

extern "C" void kernel_launch(void* const* d_in, const int* in_sizes, int n_in,
                              void* d_out, int out_size, void* d_ws, size_t ws_size,
                              hipStream_t stream) {
  (void)in_sizes; (void)n_in; (void)out_size; (void)ws_size;
  const float* x  = (const float*)d_in[0];
  const float* Wq = (const float*)d_in[1];
  const float* bq = (const float*)d_in[2];
  const float* Wk = (const float*)d_in[3];
  const float* bk = (const float*)d_in[4];
  const float* Wv = (const float*)d_in[5];
  const float* bv = (const float*)d_in[6];
  const float* Wr = (const float*)d_in[7];
  const float* br = (const float*)d_in[8];
  const float* W1 = (const float*)d_in[9];
  const float* b1 = (const float*)d_in[10];
  const float* W2 = (const float*)d_in[11];
  const float* b2 = (const float*)d_in[12];

  // ws layout: wA1 [0,73728B) | wA2 [73728,147456B) | red 33800 fp32 | bufA.
  // Cb/u/ks2 alias bufA's first 136KB: written by prep2, read by attn,
  // overwritten only later by conv3<0> (stream-serialized).
  unsigned short* wA1 = (unsigned short*)d_ws;
  unsigned short* wA2 = wA1 + 36864;
  float* red = (float*)((char*)d_ws + 147456);
  unsigned short* bufA = (unsigned short*)((char*)d_ws + 294912); // conv1 out NHWC bf16
  unsigned short* Cb = (unsigned short*)((char*)d_ws + 294912);
  float* u_  = (float*)((char*)d_ws + 294912 + 131072);
  float* ks2 = (float*)((char*)d_ws + 294912 + 133120);
  // d_out scratch: first half = attn NHWC bf16, second half = Qn NHWC bf16.
  unsigned short* bufB = (unsigned short*)d_out;
  unsigned short* bufQ = (unsigned short*)((char*)d_out + 67108864);

  prep_kernel<<<421, 256, 0, stream>>>(W1, W2, wA1, red);
  qkv_kernel<<<dim3(64, 8), 256, 0, stream>>>(x, Wq, bq, Wk, bk, bufQ, red);
  prep2_kernel<<<8, 256, 0, stream>>>(Wk, bk, Wv, bv, Wr, red, Cb, u_, ks2);
  attn_kernel<<<dim3(64, 8), 256, 0, stream>>>(bufQ, Cb, u_, ks2, br, bufB);
  conv3_kernel<0><<<dim3(8, 32, 8), 256, 0, stream>>>(
      bufB, wA1, b1, nullptr, bufA, nullptr);
  conv3_kernel<1><<<dim3(8, 32, 8), 256, 0, stream>>>(
      bufA, wA2, b2, x, nullptr, (float*)d_out);
}